// Round 2
// baseline (250.231 us; speedup 1.0000x reference)
//
#include <hip/hip_runtime.h>
#include <hip/hip_bf16.h>
#include <math.h>

#define NN 8192
#define NFEAT 1433
#define NHID 64
#define NCLASS 7
#define CAP 96

#define NB_XW1 128      // 64-row GEMM tiles (8192/64)
#define NB_BUILD 2048   // 4 adj rows per block (1 per wave)
#define KT 32
#define XSS 66          // xs row stride: (2*kk + r) mod 32 -> 2-way (free) on writes

typedef float f32x4 __attribute__((ext_vector_type(4)));

// ---------------------------------------------------------------------------
// Fused kernel: blocks [0, NB_XW1) compute XW1 = x @ W1 (VALU GEMM, LDS-tiled);
// blocks [NB_XW1, NB_XW1+NB_BUILD) stream adj rows, building the CSR + dinv.
// The GEMM blocks are VALU-bound, the build blocks HBM-bound; co-resident
// waves overlap the two pipes (MI355X: MFMA/VALU/VMEM co-schedule, time~max).
// ---------------------------------------------------------------------------
__global__ __launch_bounds__(256, 6) void k_fused(const float* __restrict__ adj,
                                                  const float* __restrict__ P,
                                                  const float* __restrict__ x,
                                                  const float* __restrict__ W1,
                                                  float* __restrict__ dinv,
                                                  int* __restrict__ cnt,
                                                  int* __restrict__ cols,
                                                  float* __restrict__ vals,
                                                  float* __restrict__ XW1) {
    __shared__ float xs[KT][XSS];   // kk-major x tile, stride 66
    __shared__ float ws[KT][64];    // kk-major W1 tile

    const int t = threadIdx.x;

    if (blockIdx.x < NB_XW1) {
        // ----------------- GEMM role: 64x64 tile, 4x4 per thread -----------
        const int m0 = blockIdx.x * 64;
        const int r0 = (t & 15) * 4;
        const int c0 = (t >> 4) * 4;
        float acc[4][4] = {};

        for (int k0 = 0; k0 < NFEAT; k0 += KT) {
            // stage x: 64 rows x 32 kk, kk-major. lanes -> consecutive k (coalesced)
            #pragma unroll
            for (int i = 0; i < 8; ++i) {
                int e = t + 256 * i;
                int r = e >> 5, kk = e & 31;
                int k = k0 + kk;
                xs[kk][r] = (k < NFEAT)
                    ? __builtin_nontemporal_load(x + (size_t)(m0 + r) * NFEAT + k)
                    : 0.f;
            }
            // stage W1: 32 kk x 64 c via float4 (reused by all blocks -> cached)
            {
                int kk = t >> 4, c4 = (t & 15) * 4;
                #pragma unroll
                for (int i = 0; i < 2; ++i) {
                    int kkk = kk + 16 * i;
                    int k = k0 + kkk;
                    float4 w = (k < NFEAT) ? *(const float4*)(W1 + (size_t)k * 64 + c4)
                                           : make_float4(0.f, 0.f, 0.f, 0.f);
                    *(float4*)(&ws[kkk][c4]) = w;
                }
            }
            __syncthreads();
            #pragma unroll
            for (int kk = 0; kk < KT; ++kk) {
                float2 a01 = *(const float2*)(&xs[kk][r0]);
                float2 a23 = *(const float2*)(&xs[kk][r0 + 2]);
                float4 b   = *(const float4*)(&ws[kk][c0]);
                float a[4] = {a01.x, a01.y, a23.x, a23.y};
                float bb[4] = {b.x, b.y, b.z, b.w};
                #pragma unroll
                for (int i = 0; i < 4; ++i)
                    #pragma unroll
                    for (int j = 0; j < 4; ++j)
                        acc[i][j] += a[i] * bb[j];
            }
            __syncthreads();
        }
        #pragma unroll
        for (int i = 0; i < 4; ++i) {
            float4 o = make_float4(acc[i][0], acc[i][1], acc[i][2], acc[i][3]);
            *(float4*)(&XW1[(size_t)(m0 + r0 + i) * 64 + c0]) = o;
        }
    } else {
        // ----------------- build role: 1 adj row per wave ------------------
        const int wave = t >> 6;
        const int lane = t & 63;
        const int row  = (blockIdx.x - NB_XW1) * 4 + wave;
        if (row >= NN) return;

        const f32x4* arow4 = (const f32x4*)(adj + (size_t)row * NN);
        const long tb = (long)row * (row + 1) / 2;
        const unsigned long long lt = (1ull << lane) - 1ull;
        const size_t rowCAP = (size_t)row * CAP;

        int base = 0;
        float dsum = 0.f;

        #pragma unroll 2
        for (int it = 0; it < NN / 256; ++it) {   // 32 iterations
            f32x4 a4 = __builtin_nontemporal_load(&arow4[it * 64 + lane]);
            int jb = (it * 64 + lane) * 4;
            #pragma unroll
            for (int s = 0; s < 4; ++s) {
                float av = a4[s];
                bool nz = (av != 0.f);
                unsigned long long mask = __ballot(nz);
                if (nz) {
                    int j = jb + s;
                    long pidx = (j <= row) ? (tb + j) : ((long)j * (j + 1) / 2 + row);
                    float p = P[pidx];
                    float v = av / (1.f + __expf(-p));   // sigmoid(p)*adj
                    int pos = base + __popcll(mask & lt);
                    if (pos < CAP) {
                        cols[rowCAP + pos] = j;
                        vals[rowCAP + pos] = v;
                    }
                    dsum += v;
                }
                base += __popcll(mask);
            }
        }
        #pragma unroll
        for (int s = 32; s; s >>= 1) dsum += __shfl_xor(dsum, s, 64);
        if (lane == 0) {
            cnt[row]  = (base < CAP) ? base : CAP;
            dinv[row] = 1.f / sqrtf(1.f + dsum);
        }
    }
}

// ---------------------------------------------------------------------------
// spmm1: h1 = relu(dinv_i*(dinv_i*XW1_i + sum_j val*dinv_j*XW1_j) + b1),
// fused HW2 = h1 @ W2 via shfl reduction. One wave per row, prefetched CSR.
// ---------------------------------------------------------------------------
__global__ __launch_bounds__(256) void k_spmm1(const float* __restrict__ XW1,
                                               const float* __restrict__ dinv,
                                               const int* __restrict__ cnt,
                                               const int* __restrict__ cols,
                                               const float* __restrict__ vals,
                                               const float* __restrict__ b1,
                                               const float* __restrict__ W2,
                                               float* __restrict__ HW2) {
    const int wave = threadIdx.x >> 6;
    const int lane = threadIdx.x & 63;
    const int row  = blockIdx.x * 4 + wave;
    if (row >= NN) return;

    const float di = dinv[row];
    float acc = di * XW1[(size_t)row * NHID + lane];
    const int c = cnt[row];
    const int*   cp = cols + (size_t)row * CAP;
    const float* vp = vals + (size_t)row * CAP;

    int jn = 0; float vn = 0.f;
    if (c > 0) { jn = cp[0]; vn = vp[0]; }
    for (int k = 0; k < c; ++k) {
        int j = jn; float v = vn;
        if (k + 1 < c) { jn = cp[k + 1]; vn = vp[k + 1]; }
        acc += v * dinv[j] * XW1[(size_t)j * NHID + lane];
    }
    float h1 = di * acc + b1[lane];
    h1 = fmaxf(h1, 0.f);

    float o[NCLASS];
    #pragma unroll
    for (int cc = 0; cc < NCLASS; ++cc) o[cc] = h1 * W2[lane * NCLASS + cc];
    #pragma unroll
    for (int cc = 0; cc < NCLASS; ++cc)
        for (int s = 32; s; s >>= 1) o[cc] += __shfl_xor(o[cc], s, 64);
    if (lane == 0) {
        #pragma unroll
        for (int cc = 0; cc < NCLASS; ++cc)
            HW2[(size_t)row * NCLASS + cc] = o[cc];
    }
}

// ---------------------------------------------------------------------------
// spmm2: h2 = norm_adj @ HW2 + b2 -> log_softmax. One wave per row.
// ---------------------------------------------------------------------------
__global__ __launch_bounds__(256) void k_spmm2(const float* __restrict__ HW2,
                                               const float* __restrict__ dinv,
                                               const int* __restrict__ cnt,
                                               const int* __restrict__ cols,
                                               const float* __restrict__ vals,
                                               const float* __restrict__ b2,
                                               float* __restrict__ out) {
    const int wave = threadIdx.x >> 6;
    const int lane = threadIdx.x & 63;
    const int row  = blockIdx.x * 4 + wave;
    if (row >= NN) return;

    const int c = cnt[row];
    const int*   cp = cols + (size_t)row * CAP;
    const float* vp = vals + (size_t)row * CAP;
    float acc[NCLASS] = {};
    for (int k = lane; k < c; k += 64) {
        int j   = cp[k];
        float w = vp[k] * dinv[j];
        #pragma unroll
        for (int cc = 0; cc < NCLASS; ++cc)
            acc[cc] += w * HW2[(size_t)j * NCLASS + cc];
    }
    #pragma unroll
    for (int cc = 0; cc < NCLASS; ++cc)
        for (int s = 32; s; s >>= 1) acc[cc] += __shfl_xor(acc[cc], s, 64);

    if (lane == 0) {
        const float di = dinv[row];
        float h[NCLASS], m = -1e30f;
        #pragma unroll
        for (int cc = 0; cc < NCLASS; ++cc) {
            h[cc] = di * (acc[cc] + di * HW2[(size_t)row * NCLASS + cc]) + b2[cc];
            m = fmaxf(m, h[cc]);
        }
        float s = 0.f;
        #pragma unroll
        for (int cc = 0; cc < NCLASS; ++cc) s += expf(h[cc] - m);
        float lse = m + logf(s);
        #pragma unroll
        for (int cc = 0; cc < NCLASS; ++cc)
            out[(size_t)row * NCLASS + cc] = h[cc] - lse;
    }
}

// ---------------------------------------------------------------------------
extern "C" void kernel_launch(void* const* d_in, const int* in_sizes, int n_in,
                              void* d_out, int out_size, void* d_ws, size_t ws_size,
                              hipStream_t stream) {
    const float* x   = (const float*)d_in[0];
    const float* adj = (const float*)d_in[1];
    const float* P   = (const float*)d_in[2];
    const float* W1  = (const float*)d_in[3];
    const float* b1  = (const float*)d_in[4];
    const float* W2  = (const float*)d_in[5];
    const float* b2  = (const float*)d_in[6];
    float* out = (float*)d_out;

    char* ws = (char*)d_ws;
    const size_t SZ_DINV = (size_t)NN * 4;
    const size_t SZ_CNT  = (size_t)NN * 4;
    const size_t SZ_COLS = (size_t)NN * CAP * 4;
    const size_t SZ_VALS = (size_t)NN * CAP * 4;
    const size_t SZ_XW1  = (size_t)NN * NHID * 4;

    float* dinv = (float*)ws;
    int*   cnt  = (int*)  (ws + SZ_DINV);
    int*   cols = (int*)  (ws + SZ_DINV + SZ_CNT);
    float* vals = (float*)(ws + SZ_DINV + SZ_CNT + SZ_COLS);
    float* XW1  = (float*)(ws + SZ_DINV + SZ_CNT + SZ_COLS + SZ_VALS);
    float* HW2  = (float*)(ws + SZ_DINV + SZ_CNT + SZ_COLS + SZ_VALS + SZ_XW1);

    k_fused<<<dim3(NB_XW1 + NB_BUILD), dim3(256), 0, stream>>>(adj, P, x, W1,
                                                               dinv, cnt, cols, vals, XW1);
    k_spmm1<<<dim3(NN / 4), dim3(256), 0, stream>>>(XW1, dinv, cnt, cols, vals, b1, W2, HW2);
    k_spmm2<<<dim3(NN / 4), dim3(256), 0, stream>>>(HW2, dinv, cnt, cols, vals, b2, out);
}

// Round 3
// 138.200 us; speedup vs baseline: 1.8106x; 1.8106x over previous
//
#include <hip/hip_runtime.h>
#include <hip/hip_bf16.h>
#include <math.h>

#define NN 8192
#define NFEAT 1433
#define NHID 64
#define NCLASS 7
#define CAP 96

#define KSPLIT 8
#define KCHUNK 180        // ceil(1433/8) = 180; covers 1440
#define NB_GEMM 1024      // 128 tiles x 8 k-chunks
#define NB_BUILD 2048     // 4 adj rows per block (1 per wave)
#define KT 32
#define XSS 66

typedef float f32x4 __attribute__((ext_vector_type(4)));

// ---------------------------------------------------------------------------
// Fused kernel, roles interleaved by blockIdx%3 (1 GEMM : 2 build) so both
// kinds are co-resident for the whole dispatch: GEMM waves (VALU-bound) hide
// latency behind build waves (HBM-bound streaming of the 256 MB adjacency).
// GEMM is K-split 8x into partial buffers (reduced by k_reduce) so it has
// 1024 blocks = 4096 waves of parallelism instead of 512.
// ---------------------------------------------------------------------------
__global__ __launch_bounds__(256, 8) void k_fused(const float* __restrict__ adj,
                                                  const float* __restrict__ P,
                                                  const float* __restrict__ x,
                                                  const float* __restrict__ W1,
                                                  float* __restrict__ dinv,
                                                  int* __restrict__ cnt,
                                                  int* __restrict__ cols,
                                                  float* __restrict__ vals,
                                                  float* __restrict__ part) {
    __shared__ float xs[KT][XSS];
    __shared__ float ws[KT][64];

    const int t = threadIdx.x;
    const int b = blockIdx.x;
    const int rmod = b % 3;
    const int g = b / 3;

    if (rmod == 0) {
        // ----------------- GEMM role: tile (64x64) x K-chunk ---------------
        const int tile = g >> 3;        // 0..127
        const int ks   = g & 7;         // 0..7
        const int m0 = tile * 64;
        const int k_begin = ks * KCHUNK;
        const int k_end   = (k_begin + KCHUNK < NFEAT) ? k_begin + KCHUNK : NFEAT;
        const int r0 = (t & 15) * 4;
        const int c0 = (t >> 4) * 4;
        float acc[4][4] = {};

        for (int k0 = k_begin; k0 < k_end; k0 += KT) {
            #pragma unroll
            for (int i = 0; i < 8; ++i) {
                int e = t + 256 * i;
                int r = e >> 5, kk = e & 31;
                int k = k0 + kk;
                xs[kk][r] = (k < k_end)
                    ? __builtin_nontemporal_load(x + (size_t)(m0 + r) * NFEAT + k)
                    : 0.f;
            }
            {
                int kk = t >> 4, c4 = (t & 15) * 4;
                #pragma unroll
                for (int i = 0; i < 2; ++i) {
                    int kkk = kk + 16 * i;
                    int k = k0 + kkk;
                    float4 w = (k < k_end) ? *(const float4*)(W1 + (size_t)k * 64 + c4)
                                           : make_float4(0.f, 0.f, 0.f, 0.f);
                    *(float4*)(&ws[kkk][c4]) = w;
                }
            }
            __syncthreads();
            #pragma unroll
            for (int kk = 0; kk < KT; ++kk) {
                float2 a01 = *(const float2*)(&xs[kk][r0]);
                float2 a23 = *(const float2*)(&xs[kk][r0 + 2]);
                float4 bv  = *(const float4*)(&ws[kk][c0]);
                float a[4] = {a01.x, a01.y, a23.x, a23.y};
                float bb[4] = {bv.x, bv.y, bv.z, bv.w};
                #pragma unroll
                for (int i = 0; i < 4; ++i)
                    #pragma unroll
                    for (int j = 0; j < 4; ++j)
                        acc[i][j] += a[i] * bb[j];
            }
            __syncthreads();
        }
        float* pout = part + (size_t)ks * NN * NHID;
        #pragma unroll
        for (int i = 0; i < 4; ++i) {
            float4 o = make_float4(acc[i][0], acc[i][1], acc[i][2], acc[i][3]);
            *(float4*)(&pout[(size_t)(m0 + r0 + i) * 64 + c0]) = o;
        }
    } else {
        // ----------------- build role: 1 adj row per wave ------------------
        const int wave = t >> 6;
        const int lane = t & 63;
        const int bid  = 2 * g + (rmod - 1);     // 0..2047
        const int row  = bid * 4 + wave;

        const f32x4* arow4 = (const f32x4*)(adj + (size_t)row * NN);
        const long tb = (long)row * (row + 1) / 2;
        const unsigned long long lt = (1ull << lane) - 1ull;
        const size_t rowCAP = (size_t)row * CAP;

        int base = 0;
        float dsum = 0.f;

        #pragma unroll 2
        for (int it = 0; it < NN / 256; ++it) {
            f32x4 a4 = __builtin_nontemporal_load(&arow4[it * 64 + lane]);
            int jb = (it * 64 + lane) * 4;
            #pragma unroll
            for (int s = 0; s < 4; ++s) {
                float av = a4[s];
                bool nz = (av != 0.f);
                unsigned long long mask = __ballot(nz);
                if (nz) {
                    int j = jb + s;
                    long pidx = (j <= row) ? (tb + j) : ((long)j * (j + 1) / 2 + row);
                    float p = P[pidx];
                    float v = av / (1.f + __expf(-p));
                    int pos = base + __popcll(mask & lt);
                    if (pos < CAP) {
                        cols[rowCAP + pos] = j;
                        vals[rowCAP + pos] = v;
                    }
                    dsum += v;
                }
                base += __popcll(mask);
            }
        }
        #pragma unroll
        for (int s = 32; s; s >>= 1) dsum += __shfl_xor(dsum, s, 64);
        if (lane == 0) {
            cnt[row]  = (base < CAP) ? base : CAP;
            dinv[row] = 1.f / sqrtf(1.f + dsum);
        }
    }
}

// ---------------------------------------------------------------------------
// Reduce the 8 K-split partials into XW1 (float4, fully coalesced).
// ---------------------------------------------------------------------------
__global__ __launch_bounds__(256) void k_reduce(const float* __restrict__ part,
                                                float* __restrict__ XW1) {
    const size_t i4 = (size_t)blockIdx.x * 256 + threadIdx.x;   // float4 index
    const f32x4* p4 = (const f32x4*)part;
    f32x4 s = p4[i4];
    #pragma unroll
    for (int ks = 1; ks < KSPLIT; ++ks)
        s += p4[(size_t)ks * (NN * NHID / 4) + i4];
    ((f32x4*)XW1)[i4] = s;
}

// ---------------------------------------------------------------------------
// spmm1: h1 = relu(dinv_i*(dinv_i*XW1_i + sum_j val*dinv_j*XW1_j) + b1),
// fused HW2 = h1 @ W2 via shfl reduction. One wave per row.
// ---------------------------------------------------------------------------
__global__ __launch_bounds__(256) void k_spmm1(const float* __restrict__ XW1,
                                               const float* __restrict__ dinv,
                                               const int* __restrict__ cnt,
                                               const int* __restrict__ cols,
                                               const float* __restrict__ vals,
                                               const float* __restrict__ b1,
                                               const float* __restrict__ W2,
                                               float* __restrict__ HW2) {
    const int wave = threadIdx.x >> 6;
    const int lane = threadIdx.x & 63;
    const int row  = blockIdx.x * 4 + wave;
    if (row >= NN) return;

    const float di = dinv[row];
    float acc = di * XW1[(size_t)row * NHID + lane];
    const int c = cnt[row];
    const int*   cp = cols + (size_t)row * CAP;
    const float* vp = vals + (size_t)row * CAP;

    int jn = 0; float vn = 0.f;
    if (c > 0) { jn = cp[0]; vn = vp[0]; }
    for (int k = 0; k < c; ++k) {
        int j = jn; float v = vn;
        if (k + 1 < c) { jn = cp[k + 1]; vn = vp[k + 1]; }
        acc += v * dinv[j] * XW1[(size_t)j * NHID + lane];
    }
    float h1 = di * acc + b1[lane];
    h1 = fmaxf(h1, 0.f);

    float o[NCLASS];
    #pragma unroll
    for (int cc = 0; cc < NCLASS; ++cc) o[cc] = h1 * W2[lane * NCLASS + cc];
    #pragma unroll
    for (int cc = 0; cc < NCLASS; ++cc)
        for (int s = 32; s; s >>= 1) o[cc] += __shfl_xor(o[cc], s, 64);
    if (lane == 0) {
        #pragma unroll
        for (int cc = 0; cc < NCLASS; ++cc)
            HW2[(size_t)row * NCLASS + cc] = o[cc];
    }
}

// ---------------------------------------------------------------------------
// spmm2: h2 = norm_adj @ HW2 + b2 -> log_softmax. One wave per row.
// ---------------------------------------------------------------------------
__global__ __launch_bounds__(256) void k_spmm2(const float* __restrict__ HW2,
                                               const float* __restrict__ dinv,
                                               const int* __restrict__ cnt,
                                               const int* __restrict__ cols,
                                               const float* __restrict__ vals,
                                               const float* __restrict__ b2,
                                               float* __restrict__ out) {
    const int wave = threadIdx.x >> 6;
    const int lane = threadIdx.x & 63;
    const int row  = blockIdx.x * 4 + wave;
    if (row >= NN) return;

    const int c = cnt[row];
    const int*   cp = cols + (size_t)row * CAP;
    const float* vp = vals + (size_t)row * CAP;
    float acc[NCLASS] = {};
    for (int k = lane; k < c; k += 64) {
        int j   = cp[k];
        float w = vp[k] * dinv[j];
        #pragma unroll
        for (int cc = 0; cc < NCLASS; ++cc)
            acc[cc] += w * HW2[(size_t)j * NCLASS + cc];
    }
    #pragma unroll
    for (int cc = 0; cc < NCLASS; ++cc)
        for (int s = 32; s; s >>= 1) acc[cc] += __shfl_xor(acc[cc], s, 64);

    if (lane == 0) {
        const float di = dinv[row];
        float h[NCLASS], m = -1e30f;
        #pragma unroll
        for (int cc = 0; cc < NCLASS; ++cc) {
            h[cc] = di * (acc[cc] + di * HW2[(size_t)row * NCLASS + cc]) + b2[cc];
            m = fmaxf(m, h[cc]);
        }
        float s = 0.f;
        #pragma unroll
        for (int cc = 0; cc < NCLASS; ++cc) s += expf(h[cc] - m);
        float lse = m + logf(s);
        #pragma unroll
        for (int cc = 0; cc < NCLASS; ++cc)
            out[(size_t)row * NCLASS + cc] = h[cc] - lse;
    }
}

// ---------------------------------------------------------------------------
extern "C" void kernel_launch(void* const* d_in, const int* in_sizes, int n_in,
                              void* d_out, int out_size, void* d_ws, size_t ws_size,
                              hipStream_t stream) {
    const float* x   = (const float*)d_in[0];
    const float* adj = (const float*)d_in[1];
    const float* P   = (const float*)d_in[2];
    const float* W1  = (const float*)d_in[3];
    const float* b1  = (const float*)d_in[4];
    const float* W2  = (const float*)d_in[5];
    const float* b2  = (const float*)d_in[6];
    float* out = (float*)d_out;

    char* ws = (char*)d_ws;
    const size_t SZ_DINV = (size_t)NN * 4;
    const size_t SZ_CNT  = (size_t)NN * 4;
    const size_t SZ_COLS = (size_t)NN * CAP * 4;
    const size_t SZ_VALS = (size_t)NN * CAP * 4;
    const size_t SZ_XW1  = (size_t)NN * NHID * 4;
    const size_t SZ_PART = (size_t)KSPLIT * NN * NHID * 4;   // 16 MB

    float* dinv = (float*)ws;
    int*   cnt  = (int*)  (ws + SZ_DINV);
    int*   cols = (int*)  (ws + SZ_DINV + SZ_CNT);
    float* vals = (float*)(ws + SZ_DINV + SZ_CNT + SZ_COLS);
    float* XW1  = (float*)(ws + SZ_DINV + SZ_CNT + SZ_COLS + SZ_VALS);
    float* HW2  = (float*)(ws + SZ_DINV + SZ_CNT + SZ_COLS + SZ_VALS + SZ_XW1);
    float* part = (float*)(ws + SZ_DINV + SZ_CNT + SZ_COLS + SZ_VALS + SZ_XW1 +
                           (size_t)NN * NCLASS * 4 + 256);

    k_fused<<<dim3(NB_GEMM + NB_BUILD), dim3(256), 0, stream>>>(adj, P, x, W1,
                                                                dinv, cnt, cols, vals, part);
    k_reduce<<<dim3(NN * NHID / 4 / 256), dim3(256), 0, stream>>>(part, XW1);
    k_spmm1<<<dim3(NN / 4), dim3(256), 0, stream>>>(XW1, dinv, cnt, cols, vals, b1, W2, HW2);
    k_spmm2<<<dim3(NN / 4), dim3(256), 0, stream>>>(HW2, dinv, cnt, cols, vals, b2, out);
}